// Round 6
// baseline (399.688 us; speedup 1.0000x reference)
//
#include <hip/hip_runtime.h>

#define BB 8
#define NN 20000
#define EE 320000
#define DD 64
#define ROWS (BB*NN)
#define TPB (NN/16)   // 1250 MFMA tiles per batch
#define EPS 1e-5f
#define CH 64  // readout chunks per batch

// Batch-major layout: h[b][n][d] -> flat (b*NN+n)*64 + d. Row r = b*NN+n.
// XCD heuristic: blocks with blockIdx.x & 7 == b work on batch b (round-robin
// block->XCD dispatch puts them all on one XCD; its 4MB L2 then holds the
// 2.56MB per-(batch,d-half) gather slice).

typedef __attribute__((ext_vector_type(8))) short short8v;
typedef __attribute__((ext_vector_type(4))) float float4v;

__device__ __forceinline__ int bcasti(int v, int l) {
  return __builtin_amdgcn_readlane(v, l);
}
__device__ __forceinline__ unsigned short bf_rtn(float f) {
  unsigned int u = __float_as_uint(f);
  return (unsigned short)((u + 0x7FFFu + ((u >> 16) & 1u)) >> 16);
}
__device__ __forceinline__ float bf_to_f(unsigned short h) {
  return __uint_as_float(((unsigned int)h) << 16);
}
__device__ __forceinline__ void split8(float4 a, float4 b, short8v& hi, short8v& lo) {
  float x[8] = {a.x, a.y, a.z, a.w, b.x, b.y, b.z, b.w};
#pragma unroll
  for (int j = 0; j < 8; ++j) {
    unsigned short h = bf_rtn(x[j]);
    hi[j] = (short)h;
    lo[j] = (short)bf_rtn(x[j] - bf_to_f(h));
  }
}

// ---------------- encoder: h = relu(x @ W_in + b_in), batch-major ----------------
__global__ __launch_bounds__(256) void k_encoder(const float* __restrict__ x,
    const float* __restrict__ Win, const float* __restrict__ bin,
    float* __restrict__ h) {
  int idx = blockIdx.x * 256 + threadIdx.x;
  int g = idx * 4;
  if (g < ROWS * DD) {
    int r = g >> 6;
    int d0 = g & 63;
    float xv = x[r];
    float4 wv = *(const float4*)&Win[d0];
    float4 bv = *(const float4*)&bin[d0];
    float4 o;
    o.x = fmaf(xv, wv.x, bv.x); o.x = o.x > 0.f ? o.x : 0.f;
    o.y = fmaf(xv, wv.y, bv.y); o.y = o.y > 0.f ? o.y : 0.f;
    o.z = fmaf(xv, wv.z, bv.z); o.z = o.z > 0.f ? o.z : 0.f;
    o.w = fmaf(xv, wv.w, bv.w); o.w = o.w > 0.f ? o.w : 0.f;
    *(float4*)&h[g] = o;
  }
}

// ---------------- degree ----------------
__global__ __launch_bounds__(256) void k_deg(const int* __restrict__ dst,
                                             int* __restrict__ cnt) {
  int e = blockIdx.x * 256 + threadIdx.x;
  if (e < EE) atomicAdd(&cnt[dst[e]], 1);
}

__global__ __launch_bounds__(256) void k_invdeg(const int* __restrict__ cnt,
                                                float* __restrict__ invdeg) {
  int n = blockIdx.x * 256 + threadIdx.x;
  if (n < NN) {
    int c = cnt[n];
    invdeg[n] = 1.0f / (float)(c > 1 ? c : 1);
  }
}

// ---------------- exclusive scan of cnt -> rowptr (single block) ----------------
__global__ __launch_bounds__(1024) void k_scan(const int* __restrict__ cnt,
                                               int* __restrict__ rowptr) {
  __shared__ int part[1024];
  int t = threadIdx.x;
  const int PER = (NN + 1023) / 1024;  // 20
  int base = t * PER;
  int s = 0;
#pragma unroll
  for (int i = 0; i < PER; ++i) {
    int idx = base + i;
    s += (idx < NN) ? cnt[idx] : 0;
  }
  part[t] = s;
  __syncthreads();
  for (int off = 1; off < 1024; off <<= 1) {
    int v = (t >= off) ? part[t - off] : 0;
    __syncthreads();
    part[t] += v;
    __syncthreads();
  }
  int run = (t > 0) ? part[t - 1] : 0;
#pragma unroll
  for (int i = 0; i < PER; ++i) {
    int idx = base + i;
    if (idx <= NN) rowptr[idx] = run;
    run += (idx < NN) ? cnt[idx] : 0;
  }
}

// ---------------- fill CSR buckets ----------------
__global__ __launch_bounds__(256) void k_fill(const int* __restrict__ src,
    const int* __restrict__ dst, const int* __restrict__ rowptr,
    int* __restrict__ cur, int* __restrict__ nbr) {
  int e = blockIdx.x * 256 + threadIdx.x;
  if (e < EE) {
    int t = dst[e];
    int pos = rowptr[t] + atomicAdd(&cur[t], 1);
    nbr[pos] = src[e];
  }
}

// ---------------- pull aggregation, per (batch, d-half) slice ----------------
// agg[b][n][d0+dl] = (sum_{s in N(n)} h[b][s][d0+dl]) * invdeg[n]
// Wave handles 2 edges at once: lanes 0-31 edge j, lanes 32-63 edge j+1.
// Gather slice = 20000*32*4B = 2.56MB -> L2-resident on the batch's XCD.
__global__ __launch_bounds__(256) void k_agg_h(const float* __restrict__ h,
    const int* __restrict__ rowptr, const int* __restrict__ nbr,
    const float* __restrict__ invdeg, float* __restrict__ agg, int d0) {
  int b = blockIdx.x & 7;
  int chunk = blockIdx.x >> 3;           // 0..1249
  int lane = threadIdx.x & 63;
  int w = threadIdx.x >> 6;
  int dl = lane & 31;
  int hi = lane >> 5;                    // 0 -> even edge, 1 -> odd edge
  const float* hb = h + ((size_t)b * NN) * DD + d0;
  for (int i = 0; i < 4; ++i) {
    int n = chunk * 16 + w * 4 + i;
    int s0 = rowptr[n], s1 = rowptr[n + 1];
    float acc0 = 0.f, acc1 = 0.f;
    for (int base = s0; base < s1; base += 64) {
      int m = s1 - base;
      if (m > 64) m = 64;
      int idxv = (base + lane < s1) ? nbr[base + lane] : 0;
      int j = 0;
      for (; j + 4 <= m; j += 4) {
        int e0 = bcasti(idxv, j), e1 = bcasti(idxv, j + 1);
        int e2 = bcasti(idxv, j + 2), e3 = bcasti(idxv, j + 3);
        int sA = hi ? e1 : e0;
        int sB = hi ? e3 : e2;
        acc0 += hb[(size_t)sA * DD + dl];
        acc1 += hb[(size_t)sB * DD + dl];
      }
      for (; j < m; j += 2) {
        int e0 = bcasti(idxv, j);
        int has1 = (j + 1 < m);
        int e1 = has1 ? bcasti(idxv, j + 1) : 0;
        int sel = hi ? e1 : e0;
        float v = hb[(size_t)sel * DD + dl];
        if (hi && !has1) v = 0.f;
        acc0 += v;
      }
    }
    float acc = acc0 + acc1;
    acc += __shfl_xor(acc, 32, 64);
    if (lane < 32) {
      agg[((size_t)b * NN + n) * DD + d0 + dl] = acc * invdeg[n];
    }
  }
}

// ---------------- MFMA node update: z = h + relu(h@Ws + agg@Wm + bias); LN ----------------
// bf16x3 split GEMM, 16-row tiles, batch-aligned tile->block mapping (XCD reuse).
// Fragment layouts per m89/m91: A lane=(row=l&15, k=(l>>4)*8+j); B lane=(k,col);
// C/D lane,reg j -> row=(l>>4)*4+j, col=l&15.
__global__ __launch_bounds__(256) void k_node_mfma(const float* __restrict__ hN,
    const float* __restrict__ aggN, const float* __restrict__ Ws,
    const float* __restrict__ Wm, const float* __restrict__ bias,
    const float* __restrict__ g, const float* __restrict__ be,
    float* __restrict__ outN) {
  __shared__ unsigned short ldsw[16384];  // [m][p][c][t][lane][8] = 32 KB
  int tid = threadIdx.x;
  int lane = tid & 63;
  int cidx = lane & 15;
  int grp = lane >> 4;

  // ---- stage split weights into LDS (once per block) ----
  for (int m = 0; m < 2; ++m) {
    const float* W = m ? Wm : Ws;
    for (int p = 0; p < 2; ++p) {
      for (int slot = tid; slot < 512; slot += 256) {
        int c = slot >> 8;
        int t = (slot >> 6) & 3;
        int l = slot & 63;
        int k0 = c * 32 + (l >> 4) * 8;
        int col = t * 16 + (l & 15);
        short8v o;
#pragma unroll
        for (int i = 0; i < 8; ++i) {
          float w = W[(k0 + i) * DD + col];
          unsigned short h16 = bf_rtn(w);
          o[i] = p ? (short)bf_rtn(w - bf_to_f(h16)) : (short)h16;
        }
        int off = (((m * 2 + p) * 2 + c) * 4 + t) * 512 + l * 8;
        *(short8v*)&ldsw[off] = o;
      }
    }
  }
  __syncthreads();

  float bias_c[4], gam_c[4], bet_c[4];
#pragma unroll
  for (int t = 0; t < 4; ++t) {
    int c = t * 16 + cidx;
    bias_c[t] = bias[c];
    gam_c[t] = g[c];
    bet_c[t] = be[c];
  }

  int job = blockIdx.x & 7;                       // batch (XCD-aligned)
  int widx = (blockIdx.x >> 3) * 4 + (tid >> 6);  // 0..255 within batch
  for (int t0 = widx; t0 < TPB; t0 += 256) {
    int r0 = job * NN + t0 * 16;
    const float* hp = hN + (size_t)(r0 + cidx) * DD + grp * 8;
    const float* ap = aggN + (size_t)(r0 + cidx) * DD + grp * 8;
    short8v ah_hi[2], ah_lo[2], am_hi[2], am_lo[2];
    {
      float4 x0 = *(const float4*)(hp);
      float4 x1 = *(const float4*)(hp + 4);
      float4 x2 = *(const float4*)(hp + 32);
      float4 x3 = *(const float4*)(hp + 36);
      split8(x0, x1, ah_hi[0], ah_lo[0]);
      split8(x2, x3, ah_hi[1], ah_lo[1]);
      float4 y0 = *(const float4*)(ap);
      float4 y1 = *(const float4*)(ap + 4);
      float4 y2 = *(const float4*)(ap + 32);
      float4 y3 = *(const float4*)(ap + 36);
      split8(y0, y1, am_hi[0], am_lo[0]);
      split8(y2, y3, am_hi[1], am_lo[1]);
    }
    float4v acc[4];
#pragma unroll
    for (int t = 0; t < 4; ++t) acc[t] = (float4v){0.f, 0.f, 0.f, 0.f};
#pragma unroll
    for (int t = 0; t < 4; ++t) {
#pragma unroll
      for (int c = 0; c < 2; ++c) {
        const short8v bsh = *(const short8v*)&ldsw[((0 * 2 + c) * 4 + t) * 512 + lane * 8];
        const short8v bsl = *(const short8v*)&ldsw[((1 * 2 + c) * 4 + t) * 512 + lane * 8];
        const short8v bmh = *(const short8v*)&ldsw[((2 * 2 + c) * 4 + t) * 512 + lane * 8];
        const short8v bml = *(const short8v*)&ldsw[((3 * 2 + c) * 4 + t) * 512 + lane * 8];
        acc[t] = __builtin_amdgcn_mfma_f32_16x16x32_bf16(ah_hi[c], bsh, acc[t], 0, 0, 0);
        acc[t] = __builtin_amdgcn_mfma_f32_16x16x32_bf16(ah_lo[c], bsh, acc[t], 0, 0, 0);
        acc[t] = __builtin_amdgcn_mfma_f32_16x16x32_bf16(ah_hi[c], bsl, acc[t], 0, 0, 0);
        acc[t] = __builtin_amdgcn_mfma_f32_16x16x32_bf16(am_hi[c], bmh, acc[t], 0, 0, 0);
        acc[t] = __builtin_amdgcn_mfma_f32_16x16x32_bf16(am_lo[c], bmh, acc[t], 0, 0, 0);
        acc[t] = __builtin_amdgcn_mfma_f32_16x16x32_bf16(am_hi[c], bml, acc[t], 0, 0, 0);
      }
    }
#pragma unroll
    for (int j = 0; j < 4; ++j) {
      int row = r0 + grp * 4 + j;
      const float* hr = hN + (size_t)row * DD;
      float zz[4];
      float part = 0.f;
#pragma unroll
      for (int t = 0; t < 4; ++t) {
        float hv = hr[t * 16 + cidx];
        float v = acc[t][j] + bias_c[t];
        v = v > 0.f ? v : 0.f;
        zz[t] = hv + v;
        part += zz[t];
      }
      part += __shfl_xor(part, 1);
      part += __shfl_xor(part, 2);
      part += __shfl_xor(part, 4);
      part += __shfl_xor(part, 8);
      float mu = part * (1.0f / 64.0f);
      float vs = 0.f;
#pragma unroll
      for (int t = 0; t < 4; ++t) {
        float d = zz[t] - mu;
        vs += d * d;
      }
      vs += __shfl_xor(vs, 1);
      vs += __shfl_xor(vs, 2);
      vs += __shfl_xor(vs, 4);
      vs += __shfl_xor(vs, 8);
      float inv = rsqrtf(vs * (1.0f / 64.0f) + EPS);
#pragma unroll
      for (int t = 0; t < 4; ++t) {
        outN[(size_t)row * DD + t * 16 + cidx] =
            fmaf(gam_c[t] * (zz[t] - mu), inv, bet_c[t]);
      }
    }
  }
}

// ---------------- readout partials: per (b, chunk) sum & max over nodes ----------------
__global__ __launch_bounds__(256) void k_reduce(const float* __restrict__ h,
    float* __restrict__ psum, float* __restrict__ pmax) {
  int lane = threadIdx.x & 63;
  int w = threadIdx.x >> 6;
  int b = blockIdx.x & 7;           // XCD-aligned
  int chunk = blockIdx.x >> 3;      // 0..63
  const int csz = (NN + CH - 1) / CH;  // 313
  int n0 = chunk * csz;
  int n1 = n0 + csz;
  if (n1 > NN) n1 = NN;
  float s = 0.f, m = -INFINITY;
  for (int n = n0 + w; n < n1; n += 4) {
    float v = h[((size_t)b * NN + n) * DD + lane];
    s += v;
    m = fmaxf(m, v);
  }
  __shared__ float ls[4][DD], lm[4][DD];
  ls[w][lane] = s;
  lm[w][lane] = m;
  __syncthreads();
  if (w == 0) {
    float ss = ls[0][lane] + ls[1][lane] + ls[2][lane] + ls[3][lane];
    float mm = fmaxf(fmaxf(lm[0][lane], lm[1][lane]),
                     fmaxf(lm[2][lane], lm[3][lane]));
    psum[((size_t)b * CH + chunk) * DD + lane] = ss;
    pmax[((size_t)b * CH + chunk) * DD + lane] = mm;
  }
}

// ---------------- final: graph_emb + MLP head ----------------
__global__ __launch_bounds__(512) void k_final(const float* __restrict__ psum,
    const float* __restrict__ pmax, const float* __restrict__ Wh1,
    const float* __restrict__ bh1, const float* __restrict__ Wh2,
    const float* __restrict__ bh2, float* __restrict__ out) {
  __shared__ float emb[BB][2 * DD];
  __shared__ float hid[BB][DD];
  int t = threadIdx.x;
  int b = t >> 6, d = t & 63;
  float s = 0.f, m = -INFINITY;
  for (int c = 0; c < CH; ++c) {
    s += psum[((size_t)b * CH + c) * DD + d];
    m = fmaxf(m, pmax[((size_t)b * CH + c) * DD + d]);
  }
  emb[b][d] = s * (1.0f / (float)NN);
  emb[b][DD + d] = m;
  __syncthreads();
  float acc = bh1[d];
#pragma unroll
  for (int k = 0; k < 2 * DD; ++k) acc = fmaf(emb[b][k], Wh1[k * DD + d], acc);
  hid[b][d] = acc > 0.f ? acc : 0.f;
  __syncthreads();
  if (d == 0) {
    float o = bh2[0];
    for (int j = 0; j < DD; ++j) o = fmaf(hid[b][j], Wh2[j], o);
    out[b] = o;
  }
}

extern "C" void kernel_launch(void* const* d_in, const int* in_sizes, int n_in,
                              void* d_out, int out_size, void* d_ws, size_t ws_size,
                              hipStream_t stream) {
  const float* x    = (const float*)d_in[0];
  const int*   ei   = (const int*)d_in[1];
  const float* Win  = (const float*)d_in[2];
  const float* bin  = (const float*)d_in[3];
  const float* Ws1  = (const float*)d_in[4];
  const float* Wm1  = (const float*)d_in[5];
  const float* bias1= (const float*)d_in[6];
  const float* g1   = (const float*)d_in[7];
  const float* be1  = (const float*)d_in[8];
  const float* Ws2  = (const float*)d_in[9];
  const float* Wm2  = (const float*)d_in[10];
  const float* bias2= (const float*)d_in[11];
  const float* g2   = (const float*)d_in[12];
  const float* be2  = (const float*)d_in[13];
  const float* Wh1  = (const float*)d_in[14];
  const float* bh1  = (const float*)d_in[15];
  const float* Wh2  = (const float*)d_in[16];
  const float* bh2  = (const float*)d_in[17];
  float* out = (float*)d_out;

  const int* src = ei;
  const int* dst = ei + EE;

  char* ws = (char*)d_ws;
  size_t off = 0;
  auto carve = [&](size_t bytes) {
    void* p = ws + off;
    off = (off + bytes + 255) & ~(size_t)255;
    return p;
  };
  const size_t hbytes = sizeof(float) * (size_t)ROWS * DD;  // 40.96 MB
  float* hA     = (float*)carve(hbytes);
  float* hB     = (float*)carve(hbytes);
  float* agg    = (float*)carve(hbytes);
  int*   cnt    = (int*)carve(sizeof(int) * NN);      // reused as 'cur'
  int*   rowptr = (int*)carve(sizeof(int) * (NN + 1));
  int*   nbr    = (int*)carve(sizeof(int) * EE);
  float* invdeg = (float*)carve(sizeof(float) * NN);
  float* psum   = (float*)carve(sizeof(float) * (size_t)BB * CH * DD);
  float* pmax   = (float*)carve(sizeof(float) * (size_t)BB * CH * DD);

  const int AGG_BLOCKS = 8 * (NN / 16);   // 10000
  const int NODE_BLOCKS = 512;            // 8 batches x 64 sub-blocks

  // encoder (batch-major output)
  k_encoder<<<(ROWS * DD / 4 + 255) / 256, 256, 0, stream>>>(x, Win, bin, hA);

  // CSR build (once; shared by both layers)
  hipMemsetAsync(cnt, 0, sizeof(int) * NN, stream);
  k_deg<<<(EE + 255) / 256, 256, 0, stream>>>(dst, cnt);
  k_invdeg<<<(NN + 255) / 256, 256, 0, stream>>>(cnt, invdeg);
  k_scan<<<1, 1024, 0, stream>>>(cnt, rowptr);
  hipMemsetAsync(cnt, 0, sizeof(int) * NN, stream);  // reuse as cursor
  k_fill<<<(EE + 255) / 256, 256, 0, stream>>>(src, dst, rowptr, cnt, nbr);

  // ---- layer 1 ----
  k_agg_h<<<AGG_BLOCKS, 256, 0, stream>>>(hA, rowptr, nbr, invdeg, agg, 0);
  k_agg_h<<<AGG_BLOCKS, 256, 0, stream>>>(hA, rowptr, nbr, invdeg, agg, 32);
  k_node_mfma<<<NODE_BLOCKS, 256, 0, stream>>>(hA, agg, Ws1, Wm1, bias1, g1,
                                               be1, hB);

  // ---- layer 2 ----
  k_agg_h<<<AGG_BLOCKS, 256, 0, stream>>>(hB, rowptr, nbr, invdeg, agg, 0);
  k_agg_h<<<AGG_BLOCKS, 256, 0, stream>>>(hB, rowptr, nbr, invdeg, agg, 32);
  k_node_mfma<<<NODE_BLOCKS, 256, 0, stream>>>(hB, agg, Ws2, Wm2, bias2, g2,
                                               be2, hA);

  // ---- readout + head ----
  k_reduce<<<8 * CH, 256, 0, stream>>>(hA, psum, pmax);
  k_final<<<1, 512, 0, stream>>>(psum, pmax, Wh1, bh1, Wh2, bh2, out);
}

// Round 7
// 285.601 us; speedup vs baseline: 1.3995x; 1.3995x over previous
//
#include <hip/hip_runtime.h>

#define BB 8
#define NN 20000
#define EE 320000
#define DD 64
#define ROWS (BB*NN)
#define TILES (ROWS/16)
#define EPS 1e-5f
#define CH 64  // readout chunks per batch

// Node-major layout: hN[n][b][d] -> flat n*512 + b*64 + d; row r=(n*8+b) is 64 contiguous floats.
// fp16 shadow hH mirrors hN (node-major): gather payload 1KB/node instead of 2KB.

typedef __attribute__((ext_vector_type(8))) short short8v;
typedef __attribute__((ext_vector_type(4))) float float4v;
typedef __attribute__((ext_vector_type(8))) _Float16 half8v;
typedef __attribute__((ext_vector_type(4))) _Float16 half4v;

__device__ __forceinline__ int bcasti(int v, int l) {
  return __builtin_amdgcn_readlane(v, l);
}
__device__ __forceinline__ unsigned short bf_rtn(float f) {
  unsigned int u = __float_as_uint(f);
  return (unsigned short)((u + 0x7FFFu + ((u >> 16) & 1u)) >> 16);
}
__device__ __forceinline__ float bf_to_f(unsigned short h) {
  return __uint_as_float(((unsigned int)h) << 16);
}
__device__ __forceinline__ void split8(float4 a, float4 b, short8v& hi, short8v& lo) {
  float x[8] = {a.x, a.y, a.z, a.w, b.x, b.y, b.z, b.w};
#pragma unroll
  for (int j = 0; j < 8; ++j) {
    unsigned short h = bf_rtn(x[j]);
    hi[j] = (short)h;
    lo[j] = (short)bf_rtn(x[j] - bf_to_f(h));
  }
}

// ---------------- encoder: hN = relu(x @ W_in + b_in) + fp16 shadow ----------------
__global__ __launch_bounds__(256) void k_encoder(const float* __restrict__ x,
    const float* __restrict__ Win, const float* __restrict__ bin,
    float* __restrict__ hN, _Float16* __restrict__ hH) {
  int idx = blockIdx.x * 256 + threadIdx.x;
  int g = idx * 4;
  if (g < NN * 512) {
    int n = g >> 9;
    int b = (g >> 6) & 7;
    int d0 = g & 63;
    float xv = x[(size_t)b * NN + n];
    float4 wv = *(const float4*)&Win[d0];
    float4 bv = *(const float4*)&bin[d0];
    float4 o;
    o.x = fmaf(xv, wv.x, bv.x); o.x = o.x > 0.f ? o.x : 0.f;
    o.y = fmaf(xv, wv.y, bv.y); o.y = o.y > 0.f ? o.y : 0.f;
    o.z = fmaf(xv, wv.z, bv.z); o.z = o.z > 0.f ? o.z : 0.f;
    o.w = fmaf(xv, wv.w, bv.w); o.w = o.w > 0.f ? o.w : 0.f;
    *(float4*)&hN[g] = o;
    half4v ho;
    ho[0] = (_Float16)o.x; ho[1] = (_Float16)o.y;
    ho[2] = (_Float16)o.z; ho[3] = (_Float16)o.w;
    *(half4v*)&hH[g] = ho;
  }
}

// ---------------- degree ----------------
__global__ __launch_bounds__(256) void k_deg(const int* __restrict__ dst,
                                             int* __restrict__ cnt) {
  int e = blockIdx.x * 256 + threadIdx.x;
  if (e < EE) atomicAdd(&cnt[dst[e]], 1);
}

// ---------------- exclusive scan of cnt -> rowptr (single block) ----------------
__global__ __launch_bounds__(1024) void k_scan(const int* __restrict__ cnt,
                                               int* __restrict__ rowptr) {
  __shared__ int part[1024];
  int t = threadIdx.x;
  const int PER = (NN + 1023) / 1024;  // 20
  int base = t * PER;
  int s = 0;
#pragma unroll
  for (int i = 0; i < PER; ++i) {
    int idx = base + i;
    s += (idx < NN) ? cnt[idx] : 0;
  }
  part[t] = s;
  __syncthreads();
  for (int off = 1; off < 1024; off <<= 1) {
    int v = (t >= off) ? part[t - off] : 0;
    __syncthreads();
    part[t] += v;
    __syncthreads();
  }
  int run = (t > 0) ? part[t - 1] : 0;
#pragma unroll
  for (int i = 0; i < PER; ++i) {
    int idx = base + i;
    if (idx <= NN) rowptr[idx] = run;
    run += (idx < NN) ? cnt[idx] : 0;
  }
}

// ---------------- fill CSR buckets ----------------
__global__ __launch_bounds__(256) void k_fill(const int* __restrict__ src,
    const int* __restrict__ dst, const int* __restrict__ rowptr,
    int* __restrict__ cur, int* __restrict__ nbr) {
  int e = blockIdx.x * 256 + threadIdx.x;
  if (e < EE) {
    int t = dst[e];
    int pos = rowptr[t] + atomicAdd(&cur[t], 1);
    nbr[pos] = src[e];
  }
}

// ---------------- pull aggregation from fp16 shadow, node-major ----------------
// aggN[n][b][d] = (sum_{s in N(n)} hH[s][b][d]) / max(deg,1)
// Lane l covers (b=l>>3, d0=(l&7)*8): one 16B half8 load per edge = full 1KB row/wave.
__global__ __launch_bounds__(256) void k_agg(const _Float16* __restrict__ hH,
    const int* __restrict__ rowptr, const int* __restrict__ nbr,
    float* __restrict__ aggN) {
  int wid = (blockIdx.x * 256 + threadIdx.x) >> 6;  // wave per node
  int lane = threadIdx.x & 63;
  if (wid >= NN) return;
  int n = wid;
  int s0 = rowptr[n], s1 = rowptr[n + 1];
  float acc[8];
#pragma unroll
  for (int k = 0; k < 8; ++k) acc[k] = 0.f;
  for (int base = s0; base < s1; base += 64) {
    int m = s1 - base;
    if (m > 64) m = 64;
    int idxv = (base + lane < s1) ? nbr[base + lane] : 0;
    int j = 0;
    // 8-edge unroll: 8 independent 16B gather loads in flight per lane
    for (; j + 8 <= m; j += 8) {
      half8v v[8];
#pragma unroll
      for (int i = 0; i < 8; ++i) {
        int s = bcasti(idxv, j + i);
        v[i] = *(const half8v*)(hH + (size_t)s * 512 + lane * 8);
      }
#pragma unroll
      for (int k = 0; k < 8; ++k) {
        float t0 = (float)v[0][k] + (float)v[1][k];
        float t1 = (float)v[2][k] + (float)v[3][k];
        float t2 = (float)v[4][k] + (float)v[5][k];
        float t3 = (float)v[6][k] + (float)v[7][k];
        acc[k] += (t0 + t1) + (t2 + t3);
      }
    }
    for (; j + 4 <= m; j += 4) {
      half8v v[4];
#pragma unroll
      for (int i = 0; i < 4; ++i) {
        int s = bcasti(idxv, j + i);
        v[i] = *(const half8v*)(hH + (size_t)s * 512 + lane * 8);
      }
#pragma unroll
      for (int k = 0; k < 8; ++k) {
        acc[k] += ((float)v[0][k] + (float)v[1][k]) +
                  ((float)v[2][k] + (float)v[3][k]);
      }
    }
    for (; j < m; ++j) {
      int s = bcasti(idxv, j);
      half8v v = *(const half8v*)(hH + (size_t)s * 512 + lane * 8);
#pragma unroll
      for (int k = 0; k < 8; ++k) acc[k] += (float)v[k];
    }
  }
  int deg = s1 - s0;
  float iv = 1.0f / (float)(deg > 1 ? deg : 1);
  // flat offset: n*512 + (l>>3)*64 + (l&7)*8 == n*512 + l*8 -> coalesced
  float4 lo = {acc[0] * iv, acc[1] * iv, acc[2] * iv, acc[3] * iv};
  float4 hi = {acc[4] * iv, acc[5] * iv, acc[6] * iv, acc[7] * iv};
  float* q = aggN + (size_t)n * 512 + lane * 8;
  *(float4*)q = lo;
  *(float4*)(q + 4) = hi;
}

// ---------------- MFMA node update: z = h + relu(h@Ws + agg@Wm + bias); LN ----------------
// bf16x3 split GEMM on 16-row tiles (layouts m89/m91-verified).
// outH (optional): fp16 shadow of output for the next layer's gather.
__global__ __launch_bounds__(256) void k_node_mfma(const float* __restrict__ hN,
    const float* __restrict__ aggN, const float* __restrict__ Ws,
    const float* __restrict__ Wm, const float* __restrict__ bias,
    const float* __restrict__ g, const float* __restrict__ be,
    float* __restrict__ outN, _Float16* __restrict__ outH, int nwaves_total) {
  __shared__ unsigned short ldsw[16384];  // [m][p][c][t][lane][8] = 32 KB
  int tid = threadIdx.x;
  int lane = tid & 63;
  int cidx = lane & 15;
  int grp = lane >> 4;

  for (int m = 0; m < 2; ++m) {
    const float* W = m ? Wm : Ws;
    for (int p = 0; p < 2; ++p) {
      for (int slot = tid; slot < 512; slot += 256) {
        int c = slot >> 8;
        int t = (slot >> 6) & 3;
        int l = slot & 63;
        int k0 = c * 32 + (l >> 4) * 8;
        int col = t * 16 + (l & 15);
        short8v o;
#pragma unroll
        for (int i = 0; i < 8; ++i) {
          float w = W[(k0 + i) * DD + col];
          unsigned short h16 = bf_rtn(w);
          o[i] = p ? (short)bf_rtn(w - bf_to_f(h16)) : (short)h16;
        }
        int off = (((m * 2 + p) * 2 + c) * 4 + t) * 512 + l * 8;
        *(short8v*)&ldsw[off] = o;
      }
    }
  }
  __syncthreads();

  float bias_c[4], gam_c[4], bet_c[4];
#pragma unroll
  for (int t = 0; t < 4; ++t) {
    int c = t * 16 + cidx;
    bias_c[t] = bias[c];
    gam_c[t] = g[c];
    bet_c[t] = be[c];
  }

  int gwave = blockIdx.x * 4 + (tid >> 6);
  for (int tile = gwave; tile < TILES; tile += nwaves_total) {
    int r0 = tile * 16;
    const float* hp = hN + (size_t)(r0 + cidx) * DD + grp * 8;
    const float* ap = aggN + (size_t)(r0 + cidx) * DD + grp * 8;
    short8v ah_hi[2], ah_lo[2], am_hi[2], am_lo[2];
    {
      float4 x0 = *(const float4*)(hp);
      float4 x1 = *(const float4*)(hp + 4);
      float4 x2 = *(const float4*)(hp + 32);
      float4 x3 = *(const float4*)(hp + 36);
      split8(x0, x1, ah_hi[0], ah_lo[0]);
      split8(x2, x3, ah_hi[1], ah_lo[1]);
      float4 y0 = *(const float4*)(ap);
      float4 y1 = *(const float4*)(ap + 4);
      float4 y2 = *(const float4*)(ap + 32);
      float4 y3 = *(const float4*)(ap + 36);
      split8(y0, y1, am_hi[0], am_lo[0]);
      split8(y2, y3, am_hi[1], am_lo[1]);
    }
    float4v acc[4];
#pragma unroll
    for (int t = 0; t < 4; ++t) acc[t] = (float4v){0.f, 0.f, 0.f, 0.f};
#pragma unroll
    for (int t = 0; t < 4; ++t) {
#pragma unroll
      for (int c = 0; c < 2; ++c) {
        const short8v bsh = *(const short8v*)&ldsw[((0 * 2 + c) * 4 + t) * 512 + lane * 8];
        const short8v bsl = *(const short8v*)&ldsw[((1 * 2 + c) * 4 + t) * 512 + lane * 8];
        const short8v bmh = *(const short8v*)&ldsw[((2 * 2 + c) * 4 + t) * 512 + lane * 8];
        const short8v bml = *(const short8v*)&ldsw[((3 * 2 + c) * 4 + t) * 512 + lane * 8];
        acc[t] = __builtin_amdgcn_mfma_f32_16x16x32_bf16(ah_hi[c], bsh, acc[t], 0, 0, 0);
        acc[t] = __builtin_amdgcn_mfma_f32_16x16x32_bf16(ah_lo[c], bsh, acc[t], 0, 0, 0);
        acc[t] = __builtin_amdgcn_mfma_f32_16x16x32_bf16(ah_hi[c], bsl, acc[t], 0, 0, 0);
        acc[t] = __builtin_amdgcn_mfma_f32_16x16x32_bf16(am_hi[c], bmh, acc[t], 0, 0, 0);
        acc[t] = __builtin_amdgcn_mfma_f32_16x16x32_bf16(am_lo[c], bmh, acc[t], 0, 0, 0);
        acc[t] = __builtin_amdgcn_mfma_f32_16x16x32_bf16(am_hi[c], bml, acc[t], 0, 0, 0);
      }
    }
#pragma unroll
    for (int j = 0; j < 4; ++j) {
      int row = r0 + grp * 4 + j;
      const float* hr = hN + (size_t)row * DD;
      float zz[4];
      float part = 0.f;
#pragma unroll
      for (int t = 0; t < 4; ++t) {
        float hv = hr[t * 16 + cidx];
        float v = acc[t][j] + bias_c[t];
        v = v > 0.f ? v : 0.f;
        zz[t] = hv + v;
        part += zz[t];
      }
      part += __shfl_xor(part, 1);
      part += __shfl_xor(part, 2);
      part += __shfl_xor(part, 4);
      part += __shfl_xor(part, 8);
      float mu = part * (1.0f / 64.0f);
      float vs = 0.f;
#pragma unroll
      for (int t = 0; t < 4; ++t) {
        float d = zz[t] - mu;
        vs += d * d;
      }
      vs += __shfl_xor(vs, 1);
      vs += __shfl_xor(vs, 2);
      vs += __shfl_xor(vs, 4);
      vs += __shfl_xor(vs, 8);
      float inv = rsqrtf(vs * (1.0f / 64.0f) + EPS);
#pragma unroll
      for (int t = 0; t < 4; ++t) {
        float val = fmaf(gam_c[t] * (zz[t] - mu), inv, bet_c[t]);
        outN[(size_t)row * DD + t * 16 + cidx] = val;
        if (outH) outH[(size_t)row * DD + t * 16 + cidx] = (_Float16)val;
      }
    }
  }
}

// ---------------- readout partials ----------------
__global__ __launch_bounds__(256) void k_reduce(const float* __restrict__ hN,
    float* __restrict__ psum, float* __restrict__ pmax) {
  int lane = threadIdx.x & 63;
  int w = threadIdx.x >> 6;
  int b = blockIdx.x / CH;
  int chunk = blockIdx.x % CH;
  const int csz = (NN + CH - 1) / CH;  // 313
  int n0 = chunk * csz;
  int n1 = n0 + csz;
  if (n1 > NN) n1 = NN;
  float s = 0.f, m = -INFINITY;
  for (int n = n0 + w; n < n1; n += 4) {
    float v = hN[(size_t)n * 512 + b * 64 + lane];
    s += v;
    m = fmaxf(m, v);
  }
  __shared__ float ls[4][DD], lm[4][DD];
  ls[w][lane] = s;
  lm[w][lane] = m;
  __syncthreads();
  if (w == 0) {
    float ss = ls[0][lane] + ls[1][lane] + ls[2][lane] + ls[3][lane];
    float mm = fmaxf(fmaxf(lm[0][lane], lm[1][lane]),
                     fmaxf(lm[2][lane], lm[3][lane]));
    psum[((size_t)b * CH + chunk) * DD + lane] = ss;
    pmax[((size_t)b * CH + chunk) * DD + lane] = mm;
  }
}

// ---------------- final: graph_emb + MLP head ----------------
__global__ __launch_bounds__(512) void k_final(const float* __restrict__ psum,
    const float* __restrict__ pmax, const float* __restrict__ Wh1,
    const float* __restrict__ bh1, const float* __restrict__ Wh2,
    const float* __restrict__ bh2, float* __restrict__ out) {
  __shared__ float emb[BB][2 * DD];
  __shared__ float hid[BB][DD];
  int t = threadIdx.x;
  int b = t >> 6, d = t & 63;
  float s = 0.f, m = -INFINITY;
  for (int c = 0; c < CH; ++c) {
    s += psum[((size_t)b * CH + c) * DD + d];
    m = fmaxf(m, pmax[((size_t)b * CH + c) * DD + d]);
  }
  emb[b][d] = s * (1.0f / (float)NN);
  emb[b][DD + d] = m;
  __syncthreads();
  float acc = bh1[d];
#pragma unroll
  for (int k = 0; k < 2 * DD; ++k) acc = fmaf(emb[b][k], Wh1[k * DD + d], acc);
  hid[b][d] = acc > 0.f ? acc : 0.f;
  __syncthreads();
  if (d == 0) {
    float o = bh2[0];
    for (int j = 0; j < DD; ++j) o = fmaf(hid[b][j], Wh2[j], o);
    out[b] = o;
  }
}

extern "C" void kernel_launch(void* const* d_in, const int* in_sizes, int n_in,
                              void* d_out, int out_size, void* d_ws, size_t ws_size,
                              hipStream_t stream) {
  const float* x    = (const float*)d_in[0];
  const int*   ei   = (const int*)d_in[1];
  const float* Win  = (const float*)d_in[2];
  const float* bin  = (const float*)d_in[3];
  const float* Ws1  = (const float*)d_in[4];
  const float* Wm1  = (const float*)d_in[5];
  const float* bias1= (const float*)d_in[6];
  const float* g1   = (const float*)d_in[7];
  const float* be1  = (const float*)d_in[8];
  const float* Ws2  = (const float*)d_in[9];
  const float* Wm2  = (const float*)d_in[10];
  const float* bias2= (const float*)d_in[11];
  const float* g2   = (const float*)d_in[12];
  const float* be2  = (const float*)d_in[13];
  const float* Wh1  = (const float*)d_in[14];
  const float* bh1  = (const float*)d_in[15];
  const float* Wh2  = (const float*)d_in[16];
  const float* bh2  = (const float*)d_in[17];
  float* out = (float*)d_out;

  const int* src = ei;
  const int* dst = ei + EE;

  char* ws = (char*)d_ws;
  size_t off = 0;
  auto carve = [&](size_t bytes) {
    void* p = ws + off;
    off = (off + bytes + 255) & ~(size_t)255;
    return p;
  };
  const size_t hbytes = sizeof(float) * (size_t)ROWS * DD;  // 40.96 MB
  float*    hA     = (float*)carve(hbytes);
  float*    hB     = (float*)carve(hbytes);
  float*    agg    = (float*)carve(hbytes);
  _Float16* hH     = (_Float16*)carve(hbytes / 2);  // fp16 gather shadow
  int*      cnt    = (int*)carve(sizeof(int) * NN);  // reused as 'cur'
  int*      rowptr = (int*)carve(sizeof(int) * (NN + 1));
  int*      nbr    = (int*)carve(sizeof(int) * EE);
  float*    psum   = (float*)carve(sizeof(float) * (size_t)BB * CH * DD);
  float*    pmax   = (float*)carve(sizeof(float) * (size_t)BB * CH * DD);

  const int NODE_BLOCKS = 512;
  const int NODE_WAVES = NODE_BLOCKS * 4;

  // encoder (node-major fp32 + fp16 shadow)
  k_encoder<<<(NN * 512 / 4 + 255) / 256, 256, 0, stream>>>(x, Win, bin, hA, hH);

  // CSR build (once; shared by both layers)
  hipMemsetAsync(cnt, 0, sizeof(int) * NN, stream);
  k_deg<<<(EE + 255) / 256, 256, 0, stream>>>(dst, cnt);
  k_scan<<<1, 1024, 0, stream>>>(cnt, rowptr);
  hipMemsetAsync(cnt, 0, sizeof(int) * NN, stream);  // reuse as cursor
  k_fill<<<(EE + 255) / 256, 256, 0, stream>>>(src, dst, rowptr, cnt, nbr);

  // ---- layer 1 ----
  k_agg<<<(NN + 3) / 4, 256, 0, stream>>>(hH, rowptr, nbr, agg);
  k_node_mfma<<<NODE_BLOCKS, 256, 0, stream>>>(hA, agg, Ws1, Wm1, bias1, g1,
                                               be1, hB, hH, NODE_WAVES);

  // ---- layer 2 ----
  k_agg<<<(NN + 3) / 4, 256, 0, stream>>>(hH, rowptr, nbr, agg);
  k_node_mfma<<<NODE_BLOCKS, 256, 0, stream>>>(hB, agg, Ws2, Wm2, bias2, g2,
                                               be2, hA, (_Float16*)nullptr,
                                               NODE_WAVES);

  // ---- readout + head ----
  k_reduce<<<BB * CH, 256, 0, stream>>>(hA, psum, pmax);
  k_final<<<1, 512, 0, stream>>>(psum, pmax, Wh1, bh1, Wh2, bh2, out);
}

// Round 8
// 263.934 us; speedup vs baseline: 1.5144x; 1.0821x over previous
//
#include <hip/hip_runtime.h>

#define BB 8
#define NN 20000
#define EE 320000
#define DD 64
#define ROWS (BB*NN)
#define TILES (ROWS/16)
#define EPS 1e-5f
#define CH 64  // readout chunks per batch

// Node-major layout: hN[n][b][d] -> flat n*512 + b*64 + d; row r=(n*8+b) is 64 contiguous floats.
// fp16 shadow hH mirrors hN; agg lives ONLY as fp16 (feeds GEMM A-operand + gather-free).

typedef __attribute__((ext_vector_type(4))) float float4v;
typedef __attribute__((ext_vector_type(8))) _Float16 half8v;
typedef __attribute__((ext_vector_type(4))) _Float16 half4v;

__device__ __forceinline__ int bcasti(int v, int l) {
  return __builtin_amdgcn_readlane(v, l);
}

// ---------------- encoder: hN = relu(x @ W_in + b_in) + fp16 shadow ----------------
__global__ __launch_bounds__(256) void k_encoder(const float* __restrict__ x,
    const float* __restrict__ Win, const float* __restrict__ bin,
    float* __restrict__ hN, _Float16* __restrict__ hH) {
  int idx = blockIdx.x * 256 + threadIdx.x;
  int g = idx * 4;
  if (g < NN * 512) {
    int n = g >> 9;
    int b = (g >> 6) & 7;
    int d0 = g & 63;
    float xv = x[(size_t)b * NN + n];
    float4 wv = *(const float4*)&Win[d0];
    float4 bv = *(const float4*)&bin[d0];
    float4 o;
    o.x = fmaf(xv, wv.x, bv.x); o.x = o.x > 0.f ? o.x : 0.f;
    o.y = fmaf(xv, wv.y, bv.y); o.y = o.y > 0.f ? o.y : 0.f;
    o.z = fmaf(xv, wv.z, bv.z); o.z = o.z > 0.f ? o.z : 0.f;
    o.w = fmaf(xv, wv.w, bv.w); o.w = o.w > 0.f ? o.w : 0.f;
    *(float4*)&hN[g] = o;
    half4v ho;
    ho[0] = (_Float16)o.x; ho[1] = (_Float16)o.y;
    ho[2] = (_Float16)o.z; ho[3] = (_Float16)o.w;
    *(half4v*)&hH[g] = ho;
  }
}

// ---------------- degree ----------------
__global__ __launch_bounds__(256) void k_deg(const int* __restrict__ dst,
                                             int* __restrict__ cnt) {
  int e = blockIdx.x * 256 + threadIdx.x;
  if (e < EE) atomicAdd(&cnt[dst[e]], 1);
}

// ---------------- exclusive scan of cnt -> rowptr (single block) ----------------
__global__ __launch_bounds__(1024) void k_scan(const int* __restrict__ cnt,
                                               int* __restrict__ rowptr) {
  __shared__ int part[1024];
  int t = threadIdx.x;
  const int PER = (NN + 1023) / 1024;  // 20
  int base = t * PER;
  int s = 0;
#pragma unroll
  for (int i = 0; i < PER; ++i) {
    int idx = base + i;
    s += (idx < NN) ? cnt[idx] : 0;
  }
  part[t] = s;
  __syncthreads();
  for (int off = 1; off < 1024; off <<= 1) {
    int v = (t >= off) ? part[t - off] : 0;
    __syncthreads();
    part[t] += v;
    __syncthreads();
  }
  int run = (t > 0) ? part[t - 1] : 0;
#pragma unroll
  for (int i = 0; i < PER; ++i) {
    int idx = base + i;
    if (idx <= NN) rowptr[idx] = run;
    run += (idx < NN) ? cnt[idx] : 0;
  }
}

// ---------------- fill CSR buckets ----------------
__global__ __launch_bounds__(256) void k_fill(const int* __restrict__ src,
    const int* __restrict__ dst, const int* __restrict__ rowptr,
    int* __restrict__ cur, int* __restrict__ nbr) {
  int e = blockIdx.x * 256 + threadIdx.x;
  if (e < EE) {
    int t = dst[e];
    int pos = rowptr[t] + atomicAdd(&cur[t], 1);
    nbr[pos] = src[e];
  }
}

// ---------------- pull aggregation from fp16 shadow -> fp16 agg ----------------
// aggH[n][b][d] = (sum_{s in N(n)} hH[s][b][d]) / max(deg,1), accumulated fp32.
__global__ __launch_bounds__(256) void k_agg(const _Float16* __restrict__ hH,
    const int* __restrict__ rowptr, const int* __restrict__ nbr,
    _Float16* __restrict__ aggH) {
  int wid = (blockIdx.x * 256 + threadIdx.x) >> 6;  // wave per node
  int lane = threadIdx.x & 63;
  if (wid >= NN) return;
  int n = wid;
  int s0 = rowptr[n], s1 = rowptr[n + 1];
  float acc[8];
#pragma unroll
  for (int k = 0; k < 8; ++k) acc[k] = 0.f;
  for (int base = s0; base < s1; base += 64) {
    int m = s1 - base;
    if (m > 64) m = 64;
    int idxv = (base + lane < s1) ? nbr[base + lane] : 0;
    int j = 0;
    // 8-edge unroll: 8 independent 16B gather loads in flight per lane
    for (; j + 8 <= m; j += 8) {
      half8v v[8];
#pragma unroll
      for (int i = 0; i < 8; ++i) {
        int s = bcasti(idxv, j + i);
        v[i] = *(const half8v*)(hH + (size_t)s * 512 + lane * 8);
      }
#pragma unroll
      for (int k = 0; k < 8; ++k) {
        float t0 = (float)v[0][k] + (float)v[1][k];
        float t1 = (float)v[2][k] + (float)v[3][k];
        float t2 = (float)v[4][k] + (float)v[5][k];
        float t3 = (float)v[6][k] + (float)v[7][k];
        acc[k] += (t0 + t1) + (t2 + t3);
      }
    }
    for (; j + 4 <= m; j += 4) {
      half8v v[4];
#pragma unroll
      for (int i = 0; i < 4; ++i) {
        int s = bcasti(idxv, j + i);
        v[i] = *(const half8v*)(hH + (size_t)s * 512 + lane * 8);
      }
#pragma unroll
      for (int k = 0; k < 8; ++k) {
        acc[k] += ((float)v[0][k] + (float)v[1][k]) +
                  ((float)v[2][k] + (float)v[3][k]);
      }
    }
    for (; j < m; ++j) {
      int s = bcasti(idxv, j);
      half8v v = *(const half8v*)(hH + (size_t)s * 512 + lane * 8);
#pragma unroll
      for (int k = 0; k < 8; ++k) acc[k] += (float)v[k];
    }
  }
  int deg = s1 - s0;
  float iv = 1.0f / (float)(deg > 1 ? deg : 1);
  half8v o;
#pragma unroll
  for (int k = 0; k < 8; ++k) o[k] = (_Float16)(acc[k] * iv);
  *(half8v*)(aggH + (size_t)n * 512 + lane * 8) = o;  // coalesced 16B/lane
}

// ---------------- MFMA node update: z = h + relu(h@Ws + agg@Wm + bias); LN ----------------
// f16 MFMA: A = fp16 (hH / aggH, loaded directly — no conversion);
// W = fp16 hi+lo split staged in LDS (split error ~2^-21).
// Fragment layouts per m89/m91: A lane=(row=l&15, k=(l>>4)*8+j); B lane=(k,col);
// C/D lane,reg j -> row=(l>>4)*4+j, col=l&15.  32 MFMA / 16-row tile.
__global__ __launch_bounds__(256) void k_node_mfma(const float* __restrict__ hN,
    const _Float16* __restrict__ hH, const _Float16* __restrict__ aggH,
    const float* __restrict__ Ws, const float* __restrict__ Wm,
    const float* __restrict__ bias, const float* __restrict__ g,
    const float* __restrict__ be, float* __restrict__ outN,
    _Float16* __restrict__ outH, int nwaves_total) {
  __shared__ _Float16 ldsw[16384];  // [m][p][c][t][lane][8] = 32 KB
  int tid = threadIdx.x;
  int lane = tid & 63;
  int cidx = lane & 15;
  int grp = lane >> 4;

  // ---- stage fp16 hi/lo split weights into LDS (each W element loaded once) ----
  for (int m = 0; m < 2; ++m) {
    const float* W = m ? Wm : Ws;
    for (int slot = tid; slot < 512; slot += 256) {
      int c = slot >> 8;
      int t = (slot >> 6) & 3;
      int l = slot & 63;
      int k0 = c * 32 + (l >> 4) * 8;
      int col = t * 16 + (l & 15);
      half8v ohi, olo;
#pragma unroll
      for (int i = 0; i < 8; ++i) {
        float w = W[(k0 + i) * DD + col];
        _Float16 hi = (_Float16)w;
        ohi[i] = hi;
        olo[i] = (_Float16)(w - (float)hi);
      }
      int ohf = (((m * 2 + 0) * 2 + c) * 4 + t) * 512 + l * 8;
      int olf = (((m * 2 + 1) * 2 + c) * 4 + t) * 512 + l * 8;
      *(half8v*)&ldsw[ohf] = ohi;
      *(half8v*)&ldsw[olf] = olo;
    }
  }
  __syncthreads();

  float bias_c[4], gam_c[4], bet_c[4];
#pragma unroll
  for (int t = 0; t < 4; ++t) {
    int c = t * 16 + cidx;
    bias_c[t] = bias[c];
    gam_c[t] = g[c];
    bet_c[t] = be[c];
  }

  int gwave = blockIdx.x * 4 + (tid >> 6);
  for (int tile = gwave; tile < TILES; tile += nwaves_total) {
    int r0 = tile * 16;
    // ---- A fragments: direct fp16 loads, zero conversion ----
    const _Float16* hp = hH + (size_t)(r0 + cidx) * DD;
    const _Float16* ap = aggH + (size_t)(r0 + cidx) * DD;
    half8v ah[2], am[2];
    ah[0] = *(const half8v*)(hp + grp * 8);
    ah[1] = *(const half8v*)(hp + 32 + grp * 8);
    am[0] = *(const half8v*)(ap + grp * 8);
    am[1] = *(const half8v*)(ap + 32 + grp * 8);

    float4v acc[4];
#pragma unroll
    for (int t = 0; t < 4; ++t) acc[t] = (float4v){0.f, 0.f, 0.f, 0.f};
#pragma unroll
    for (int t = 0; t < 4; ++t) {
#pragma unroll
      for (int c = 0; c < 2; ++c) {
        const half8v bsh = *(const half8v*)&ldsw[((0 * 2 + c) * 4 + t) * 512 + lane * 8];
        const half8v bsl = *(const half8v*)&ldsw[((2 + c) * 4 + t) * 512 + lane * 8];
        const half8v bmh = *(const half8v*)&ldsw[((4 + c) * 4 + t) * 512 + lane * 8];
        const half8v bml = *(const half8v*)&ldsw[((6 + c) * 4 + t) * 512 + lane * 8];
        acc[t] = __builtin_amdgcn_mfma_f32_16x16x32_f16(ah[c], bsh, acc[t], 0, 0, 0);
        acc[t] = __builtin_amdgcn_mfma_f32_16x16x32_f16(ah[c], bsl, acc[t], 0, 0, 0);
        acc[t] = __builtin_amdgcn_mfma_f32_16x16x32_f16(am[c], bmh, acc[t], 0, 0, 0);
        acc[t] = __builtin_amdgcn_mfma_f32_16x16x32_f16(am[c], bml, acc[t], 0, 0, 0);
      }
    }
    // ---- epilogue: residual (fp32 h) + relu + LayerNorm ----
#pragma unroll
    for (int j = 0; j < 4; ++j) {
      int row = r0 + grp * 4 + j;
      const float* hr = hN + (size_t)row * DD;
      float zz[4];
      float part = 0.f;
#pragma unroll
      for (int t = 0; t < 4; ++t) {
        float hv = hr[t * 16 + cidx];
        float v = acc[t][j] + bias_c[t];
        v = v > 0.f ? v : 0.f;
        zz[t] = hv + v;
        part += zz[t];
      }
      part += __shfl_xor(part, 1);
      part += __shfl_xor(part, 2);
      part += __shfl_xor(part, 4);
      part += __shfl_xor(part, 8);
      float mu = part * (1.0f / 64.0f);
      float vs = 0.f;
#pragma unroll
      for (int t = 0; t < 4; ++t) {
        float d = zz[t] - mu;
        vs += d * d;
      }
      vs += __shfl_xor(vs, 1);
      vs += __shfl_xor(vs, 2);
      vs += __shfl_xor(vs, 4);
      vs += __shfl_xor(vs, 8);
      float inv = rsqrtf(vs * (1.0f / 64.0f) + EPS);
#pragma unroll
      for (int t = 0; t < 4; ++t) {
        float val = fmaf(gam_c[t] * (zz[t] - mu), inv, bet_c[t]);
        outN[(size_t)row * DD + t * 16 + cidx] = val;
        if (outH) outH[(size_t)row * DD + t * 16 + cidx] = (_Float16)val;
      }
    }
  }
}

// ---------------- readout partials ----------------
__global__ __launch_bounds__(256) void k_reduce(const float* __restrict__ hN,
    float* __restrict__ psum, float* __restrict__ pmax) {
  int lane = threadIdx.x & 63;
  int w = threadIdx.x >> 6;
  int b = blockIdx.x / CH;
  int chunk = blockIdx.x % CH;
  const int csz = (NN + CH - 1) / CH;  // 313
  int n0 = chunk * csz;
  int n1 = n0 + csz;
  if (n1 > NN) n1 = NN;
  float s = 0.f, m = -INFINITY;
  for (int n = n0 + w; n < n1; n += 4) {
    float v = hN[(size_t)n * 512 + b * 64 + lane];
    s += v;
    m = fmaxf(m, v);
  }
  __shared__ float ls[4][DD], lm[4][DD];
  ls[w][lane] = s;
  lm[w][lane] = m;
  __syncthreads();
  if (w == 0) {
    float ss = ls[0][lane] + ls[1][lane] + ls[2][lane] + ls[3][lane];
    float mm = fmaxf(fmaxf(lm[0][lane], lm[1][lane]),
                     fmaxf(lm[2][lane], lm[3][lane]));
    psum[((size_t)b * CH + chunk) * DD + lane] = ss;
    pmax[((size_t)b * CH + chunk) * DD + lane] = mm;
  }
}

// ---------------- final: graph_emb + MLP head ----------------
__global__ __launch_bounds__(512) void k_final(const float* __restrict__ psum,
    const float* __restrict__ pmax, const float* __restrict__ Wh1,
    const float* __restrict__ bh1, const float* __restrict__ Wh2,
    const float* __restrict__ bh2, float* __restrict__ out) {
  __shared__ float emb[BB][2 * DD];
  __shared__ float hid[BB][DD];
  int t = threadIdx.x;
  int b = t >> 6, d = t & 63;
  float s = 0.f, m = -INFINITY;
  for (int c = 0; c < CH; ++c) {
    s += psum[((size_t)b * CH + c) * DD + d];
    m = fmaxf(m, pmax[((size_t)b * CH + c) * DD + d]);
  }
  emb[b][d] = s * (1.0f / (float)NN);
  emb[b][DD + d] = m;
  __syncthreads();
  float acc = bh1[d];
#pragma unroll
  for (int k = 0; k < 2 * DD; ++k) acc = fmaf(emb[b][k], Wh1[k * DD + d], acc);
  hid[b][d] = acc > 0.f ? acc : 0.f;
  __syncthreads();
  if (d == 0) {
    float o = bh2[0];
    for (int j = 0; j < DD; ++j) o = fmaf(hid[b][j], Wh2[j], o);
    out[b] = o;
  }
}

extern "C" void kernel_launch(void* const* d_in, const int* in_sizes, int n_in,
                              void* d_out, int out_size, void* d_ws, size_t ws_size,
                              hipStream_t stream) {
  const float* x    = (const float*)d_in[0];
  const int*   ei   = (const int*)d_in[1];
  const float* Win  = (const float*)d_in[2];
  const float* bin  = (const float*)d_in[3];
  const float* Ws1  = (const float*)d_in[4];
  const float* Wm1  = (const float*)d_in[5];
  const float* bias1= (const float*)d_in[6];
  const float* g1   = (const float*)d_in[7];
  const float* be1  = (const float*)d_in[8];
  const float* Ws2  = (const float*)d_in[9];
  const float* Wm2  = (const float*)d_in[10];
  const float* bias2= (const float*)d_in[11];
  const float* g2   = (const float*)d_in[12];
  const float* be2  = (const float*)d_in[13];
  const float* Wh1  = (const float*)d_in[14];
  const float* bh1  = (const float*)d_in[15];
  const float* Wh2  = (const float*)d_in[16];
  const float* bh2  = (const float*)d_in[17];
  float* out = (float*)d_out;

  const int* src = ei;
  const int* dst = ei + EE;

  char* ws = (char*)d_ws;
  size_t off = 0;
  auto carve = [&](size_t bytes) {
    void* p = ws + off;
    off = (off + bytes + 255) & ~(size_t)255;
    return p;
  };
  const size_t hbytes = sizeof(float) * (size_t)ROWS * DD;  // 40.96 MB
  float*    hA     = (float*)carve(hbytes);
  float*    hB     = (float*)carve(hbytes);
  _Float16* aggH   = (_Float16*)carve(hbytes / 2);  // fp16 agg (GEMM A-operand)
  _Float16* hH     = (_Float16*)carve(hbytes / 2);  // fp16 gather shadow
  int*      cnt    = (int*)carve(sizeof(int) * NN);  // reused as 'cur'
  int*      rowptr = (int*)carve(sizeof(int) * (NN + 1));
  int*      nbr    = (int*)carve(sizeof(int) * EE);
  float*    psum   = (float*)carve(sizeof(float) * (size_t)BB * CH * DD);
  float*    pmax   = (float*)carve(sizeof(float) * (size_t)BB * CH * DD);

  const int NODE_BLOCKS = 2048;  // grid-stride over 80000 tiles; ~5 blocks/CU LDS-limited
  const int NODE_WAVES = NODE_BLOCKS * 4;

  // encoder (node-major fp32 + fp16 shadow)
  k_encoder<<<(NN * 512 / 4 + 255) / 256, 256, 0, stream>>>(x, Win, bin, hA, hH);

  // CSR build (once; shared by both layers)
  hipMemsetAsync(cnt, 0, sizeof(int) * NN, stream);
  k_deg<<<(EE + 255) / 256, 256, 0, stream>>>(dst, cnt);
  k_scan<<<1, 1024, 0, stream>>>(cnt, rowptr);
  hipMemsetAsync(cnt, 0, sizeof(int) * NN, stream);  // reuse as cursor
  k_fill<<<(EE + 255) / 256, 256, 0, stream>>>(src, dst, rowptr, cnt, nbr);

  // ---- layer 1 ----
  k_agg<<<(NN + 3) / 4, 256, 0, stream>>>(hH, rowptr, nbr, aggH);
  k_node_mfma<<<NODE_BLOCKS, 256, 0, stream>>>(hA, hH, aggH, Ws1, Wm1, bias1,
                                               g1, be1, hB, hH, NODE_WAVES);

  // ---- layer 2 ----
  k_agg<<<(NN + 3) / 4, 256, 0, stream>>>(hH, rowptr, nbr, aggH);
  k_node_mfma<<<NODE_BLOCKS, 256, 0, stream>>>(hB, hH, aggH, Ws2, Wm2, bias2,
                                               g2, be2, hA, (_Float16*)nullptr,
                                               NODE_WAVES);

  // ---- readout + head ----
  k_reduce<<<BB * CH, 256, 0, stream>>>(hA, psum, pmax);
  k_final<<<1, 512, 0, stream>>>(psum, pmax, Wh1, bh1, Wh2, bh2, out);
}

// Round 9
// 248.325 us; speedup vs baseline: 1.6095x; 1.0629x over previous
//
#include <hip/hip_runtime.h>

#define BB 8
#define NN 20000
#define EE 320000
#define DD 64
#define ROWS (BB*NN)
#define TILES (ROWS/16)
#define EPS 1e-5f
#define CH 64  // readout chunks per batch

// Full fp16 storage, fp32 compute. Node-major: hH[n][b][d] -> flat n*512+b*64+d;
// row r=(n*8+b) is 64 contiguous halfs (128B). All GEMM via f16 MFMA with
// hi+lo split weights (split error ~2^-21); accumulation always fp32.

typedef __attribute__((ext_vector_type(4))) float float4v;
typedef __attribute__((ext_vector_type(8))) _Float16 half8v;

__device__ __forceinline__ int bcasti(int v, int l) {
  return __builtin_amdgcn_readlane(v, l);
}

// ---------------- encoder: hH = relu(x @ W_in + b_in) (fp16 out) + cnt zero ----------------
__global__ __launch_bounds__(256) void k_encoder(const float* __restrict__ x,
    const float* __restrict__ Win, const float* __restrict__ bin,
    _Float16* __restrict__ hH, int* __restrict__ cnt) {
  int idx = blockIdx.x * 256 + threadIdx.x;
  if (idx < NN) cnt[idx] = 0;  // stream-ordered before k_deg
  int g = idx * 8;  // 8 halfs per thread
  if (g < NN * 512) {
    int n = g >> 9;
    int b = (g >> 6) & 7;
    int d0 = g & 63;
    float xv = x[(size_t)b * NN + n];
    float4 w0 = *(const float4*)&Win[d0];
    float4 w1 = *(const float4*)&Win[d0 + 4];
    float4 b0 = *(const float4*)&bin[d0];
    float4 b1 = *(const float4*)&bin[d0 + 4];
    float o[8];
    o[0] = fmaf(xv, w0.x, b0.x); o[1] = fmaf(xv, w0.y, b0.y);
    o[2] = fmaf(xv, w0.z, b0.z); o[3] = fmaf(xv, w0.w, b0.w);
    o[4] = fmaf(xv, w1.x, b1.x); o[5] = fmaf(xv, w1.y, b1.y);
    o[6] = fmaf(xv, w1.z, b1.z); o[7] = fmaf(xv, w1.w, b1.w);
    half8v ho;
#pragma unroll
    for (int k = 0; k < 8; ++k) ho[k] = (_Float16)(o[k] > 0.f ? o[k] : 0.f);
    *(half8v*)&hH[g] = ho;
  }
}

// ---------------- degree ----------------
__global__ __launch_bounds__(256) void k_deg(const int* __restrict__ dst,
                                             int* __restrict__ cnt) {
  int e = blockIdx.x * 256 + threadIdx.x;
  if (e < EE) atomicAdd(&cnt[dst[e]], 1);
}

// ---------------- exclusive scan: cnt -> rowptr, and cursor copy ----------------
__global__ __launch_bounds__(1024) void k_scan(const int* __restrict__ cnt,
                                               int* __restrict__ rowptr,
                                               int* __restrict__ cur) {
  __shared__ int part[1024];
  int t = threadIdx.x;
  const int PER = (NN + 1023) / 1024;  // 20
  int base = t * PER;
  int s = 0;
#pragma unroll
  for (int i = 0; i < PER; ++i) {
    int idx = base + i;
    s += (idx < NN) ? cnt[idx] : 0;
  }
  part[t] = s;
  __syncthreads();
  for (int off = 1; off < 1024; off <<= 1) {
    int v = (t >= off) ? part[t - off] : 0;
    __syncthreads();
    part[t] += v;
    __syncthreads();
  }
  int run = (t > 0) ? part[t - 1] : 0;
#pragma unroll
  for (int i = 0; i < PER; ++i) {
    int idx = base + i;
    if (idx <= NN) rowptr[idx] = run;
    if (idx < NN) cur[idx] = run;  // cursor pre-initialized to rowptr
    run += (idx < NN) ? cnt[idx] : 0;
  }
}

// ---------------- fill CSR buckets (cursor already = rowptr) ----------------
__global__ __launch_bounds__(256) void k_fill(const int* __restrict__ src,
    const int* __restrict__ dst, int* __restrict__ cur,
    int* __restrict__ nbr) {
  int e = blockIdx.x * 256 + threadIdx.x;
  if (e < EE) {
    int pos = atomicAdd(&cur[dst[e]], 1);
    nbr[pos] = src[e];
  }
}

// ---------------- pull aggregation fp16 -> fp16 (fp32 accum) ----------------
// aggH[n][b][d] = (sum_{s in N(n)} hH[s][b][d]) / max(deg,1)
__global__ __launch_bounds__(256) void k_agg(const _Float16* __restrict__ hH,
    const int* __restrict__ rowptr, const int* __restrict__ nbr,
    _Float16* __restrict__ aggH) {
  int wid = (blockIdx.x * 256 + threadIdx.x) >> 6;  // wave per node
  int lane = threadIdx.x & 63;
  if (wid >= NN) return;
  int n = wid;
  int s0 = rowptr[n], s1 = rowptr[n + 1];
  float acc[8];
#pragma unroll
  for (int k = 0; k < 8; ++k) acc[k] = 0.f;
  for (int base = s0; base < s1; base += 64) {
    int m = s1 - base;
    if (m > 64) m = 64;
    int idxv = (base + lane < s1) ? nbr[base + lane] : 0;
    int j = 0;
    for (; j + 8 <= m; j += 8) {
      half8v v[8];
#pragma unroll
      for (int i = 0; i < 8; ++i) {
        int s = bcasti(idxv, j + i);
        v[i] = *(const half8v*)(hH + (size_t)s * 512 + lane * 8);
      }
#pragma unroll
      for (int k = 0; k < 8; ++k) {
        float t0 = (float)v[0][k] + (float)v[1][k];
        float t1 = (float)v[2][k] + (float)v[3][k];
        float t2 = (float)v[4][k] + (float)v[5][k];
        float t3 = (float)v[6][k] + (float)v[7][k];
        acc[k] += (t0 + t1) + (t2 + t3);
      }
    }
    for (; j + 4 <= m; j += 4) {
      half8v v[4];
#pragma unroll
      for (int i = 0; i < 4; ++i) {
        int s = bcasti(idxv, j + i);
        v[i] = *(const half8v*)(hH + (size_t)s * 512 + lane * 8);
      }
#pragma unroll
      for (int k = 0; k < 8; ++k) {
        acc[k] += ((float)v[0][k] + (float)v[1][k]) +
                  ((float)v[2][k] + (float)v[3][k]);
      }
    }
    for (; j < m; ++j) {
      int s = bcasti(idxv, j);
      half8v v = *(const half8v*)(hH + (size_t)s * 512 + lane * 8);
#pragma unroll
      for (int k = 0; k < 8; ++k) acc[k] += (float)v[k];
    }
  }
  int deg = s1 - s0;
  float iv = 1.0f / (float)(deg > 1 ? deg : 1);
  half8v o;
#pragma unroll
  for (int k = 0; k < 8; ++k) o[k] = (_Float16)(acc[k] * iv);
  *(half8v*)(aggH + (size_t)n * 512 + lane * 8) = o;
}

// ---------------- MFMA node update: z = h + relu(h@Ws + agg@Wm + bias); LN ----------------
// A = fp16 direct (hH/aggH); W = fp16 hi+lo split in LDS. Residual from hH.
// Fragment layouts (m89/m91): A lane=(row=l&15, k=(l>>4)*8+j); B lane=(k,col);
// C/D lane,reg j -> row=(l>>4)*4+j, col=l&15.  32 MFMA / 16-row tile.
__global__ __launch_bounds__(256) void k_node_mfma(
    const _Float16* __restrict__ hH, const _Float16* __restrict__ aggH,
    const float* __restrict__ Ws, const float* __restrict__ Wm,
    const float* __restrict__ bias, const float* __restrict__ g,
    const float* __restrict__ be, _Float16* __restrict__ outH,
    int nwaves_total) {
  __shared__ _Float16 ldsw[16384];  // [m][p][c][t][lane][8] = 32 KB
  int tid = threadIdx.x;
  int lane = tid & 63;
  int cidx = lane & 15;
  int grp = lane >> 4;

  for (int m = 0; m < 2; ++m) {
    const float* W = m ? Wm : Ws;
    for (int slot = tid; slot < 512; slot += 256) {
      int c = slot >> 8;
      int t = (slot >> 6) & 3;
      int l = slot & 63;
      int k0 = c * 32 + (l >> 4) * 8;
      int col = t * 16 + (l & 15);
      half8v ohi, olo;
#pragma unroll
      for (int i = 0; i < 8; ++i) {
        float w = W[(k0 + i) * DD + col];
        _Float16 hi = (_Float16)w;
        ohi[i] = hi;
        olo[i] = (_Float16)(w - (float)hi);
      }
      *(half8v*)&ldsw[(((m * 2 + 0) * 2 + c) * 4 + t) * 512 + l * 8] = ohi;
      *(half8v*)&ldsw[(((m * 2 + 1) * 2 + c) * 4 + t) * 512 + l * 8] = olo;
    }
  }
  __syncthreads();

  float bias_c[4], gam_c[4], bet_c[4];
#pragma unroll
  for (int t = 0; t < 4; ++t) {
    int c = t * 16 + cidx;
    bias_c[t] = bias[c];
    gam_c[t] = g[c];
    bet_c[t] = be[c];
  }

  int gwave = blockIdx.x * 4 + (tid >> 6);
  for (int tile = gwave; tile < TILES; tile += nwaves_total) {
    int r0 = tile * 16;
    const _Float16* hp = hH + (size_t)(r0 + cidx) * DD;
    const _Float16* ap = aggH + (size_t)(r0 + cidx) * DD;
    half8v ah[2], am[2];
    ah[0] = *(const half8v*)(hp + grp * 8);
    ah[1] = *(const half8v*)(hp + 32 + grp * 8);
    am[0] = *(const half8v*)(ap + grp * 8);
    am[1] = *(const half8v*)(ap + 32 + grp * 8);

    float4v acc[4];
#pragma unroll
    for (int t = 0; t < 4; ++t) acc[t] = (float4v){0.f, 0.f, 0.f, 0.f};
#pragma unroll
    for (int t = 0; t < 4; ++t) {
#pragma unroll
      for (int c = 0; c < 2; ++c) {
        const half8v bsh = *(const half8v*)&ldsw[((0 + c) * 4 + t) * 512 + lane * 8];
        const half8v bsl = *(const half8v*)&ldsw[((2 + c) * 4 + t) * 512 + lane * 8];
        const half8v bmh = *(const half8v*)&ldsw[((4 + c) * 4 + t) * 512 + lane * 8];
        const half8v bml = *(const half8v*)&ldsw[((6 + c) * 4 + t) * 512 + lane * 8];
        acc[t] = __builtin_amdgcn_mfma_f32_16x16x32_f16(ah[c], bsh, acc[t], 0, 0, 0);
        acc[t] = __builtin_amdgcn_mfma_f32_16x16x32_f16(ah[c], bsl, acc[t], 0, 0, 0);
        acc[t] = __builtin_amdgcn_mfma_f32_16x16x32_f16(am[c], bmh, acc[t], 0, 0, 0);
        acc[t] = __builtin_amdgcn_mfma_f32_16x16x32_f16(am[c], bml, acc[t], 0, 0, 0);
      }
    }
    // epilogue: residual (fp16 h, L1-hot) + relu + LayerNorm, fp32 math
#pragma unroll
    for (int j = 0; j < 4; ++j) {
      int row = r0 + grp * 4 + j;
      const _Float16* hr = hH + (size_t)row * DD;
      float zz[4];
      float part = 0.f;
#pragma unroll
      for (int t = 0; t < 4; ++t) {
        float hv = (float)hr[t * 16 + cidx];
        float v = acc[t][j] + bias_c[t];
        v = v > 0.f ? v : 0.f;
        zz[t] = hv + v;
        part += zz[t];
      }
      part += __shfl_xor(part, 1);
      part += __shfl_xor(part, 2);
      part += __shfl_xor(part, 4);
      part += __shfl_xor(part, 8);
      float mu = part * (1.0f / 64.0f);
      float vs = 0.f;
#pragma unroll
      for (int t = 0; t < 4; ++t) {
        float d = zz[t] - mu;
        vs += d * d;
      }
      vs += __shfl_xor(vs, 1);
      vs += __shfl_xor(vs, 2);
      vs += __shfl_xor(vs, 4);
      vs += __shfl_xor(vs, 8);
      float inv = rsqrtf(vs * (1.0f / 64.0f) + EPS);
#pragma unroll
      for (int t = 0; t < 4; ++t) {
        float val = fmaf(gam_c[t] * (zz[t] - mu), inv, bet_c[t]);
        outH[(size_t)row * DD + t * 16 + cidx] = (_Float16)val;
      }
    }
  }
}

// ---------------- readout partials (fp16 in, fp32 accum) ----------------
__global__ __launch_bounds__(256) void k_reduce(const _Float16* __restrict__ hH,
    float* __restrict__ psum, float* __restrict__ pmax) {
  int lane = threadIdx.x & 63;
  int w = threadIdx.x >> 6;
  int b = blockIdx.x / CH;
  int chunk = blockIdx.x % CH;
  const int csz = (NN + CH - 1) / CH;  // 313
  int n0 = chunk * csz;
  int n1 = n0 + csz;
  if (n1 > NN) n1 = NN;
  float s = 0.f, m = -INFINITY;
  for (int n = n0 + w; n < n1; n += 4) {
    float v = (float)hH[(size_t)n * 512 + b * 64 + lane];
    s += v;
    m = fmaxf(m, v);
  }
  __shared__ float ls[4][DD], lm[4][DD];
  ls[w][lane] = s;
  lm[w][lane] = m;
  __syncthreads();
  if (w == 0) {
    float ss = ls[0][lane] + ls[1][lane] + ls[2][lane] + ls[3][lane];
    float mm = fmaxf(fmaxf(lm[0][lane], lm[1][lane]),
                     fmaxf(lm[2][lane], lm[3][lane]));
    psum[((size_t)b * CH + chunk) * DD + lane] = ss;
    pmax[((size_t)b * CH + chunk) * DD + lane] = mm;
  }
}

// ---------------- final: graph_emb + MLP head ----------------
__global__ __launch_bounds__(512) void k_final(const float* __restrict__ psum,
    const float* __restrict__ pmax, const float* __restrict__ Wh1,
    const float* __restrict__ bh1, const float* __restrict__ Wh2,
    const float* __restrict__ bh2, float* __restrict__ out) {
  __shared__ float emb[BB][2 * DD];
  __shared__ float hid[BB][DD];
  int t = threadIdx.x;
  int b = t >> 6, d = t & 63;
  float s = 0.f, m = -INFINITY;
  for (int c = 0; c < CH; ++c) {
    s += psum[((size_t)b * CH + c) * DD + d];
    m = fmaxf(m, pmax[((size_t)b * CH + c) * DD + d]);
  }
  emb[b][d] = s * (1.0f / (float)NN);
  emb[b][DD + d] = m;
  __syncthreads();
  float acc = bh1[d];
#pragma unroll
  for (int k = 0; k < 2 * DD; ++k) acc = fmaf(emb[b][k], Wh1[k * DD + d], acc);
  hid[b][d] = acc > 0.f ? acc : 0.f;
  __syncthreads();
  if (d == 0) {
    float o = bh2[0];
    for (int j = 0; j < DD; ++j) o = fmaf(hid[b][j], Wh2[j], o);
    out[b] = o;
  }
}

extern "C" void kernel_launch(void* const* d_in, const int* in_sizes, int n_in,
                              void* d_out, int out_size, void* d_ws, size_t ws_size,
                              hipStream_t stream) {
  const float* x    = (const float*)d_in[0];
  const int*   ei   = (const int*)d_in[1];
  const float* Win  = (const float*)d_in[2];
  const float* bin  = (const float*)d_in[3];
  const float* Ws1  = (const float*)d_in[4];
  const float* Wm1  = (const float*)d_in[5];
  const float* bias1= (const float*)d_in[6];
  const float* g1   = (const float*)d_in[7];
  const float* be1  = (const float*)d_in[8];
  const float* Ws2  = (const float*)d_in[9];
  const float* Wm2  = (const float*)d_in[10];
  const float* bias2= (const float*)d_in[11];
  const float* g2   = (const float*)d_in[12];
  const float* be2  = (const float*)d_in[13];
  const float* Wh1  = (const float*)d_in[14];
  const float* bh1  = (const float*)d_in[15];
  const float* Wh2  = (const float*)d_in[16];
  const float* bh2  = (const float*)d_in[17];
  float* out = (float*)d_out;

  const int* src = ei;
  const int* dst = ei + EE;

  char* ws = (char*)d_ws;
  size_t off = 0;
  auto carve = [&](size_t bytes) {
    void* p = ws + off;
    off = (off + bytes + 255) & ~(size_t)255;
    return p;
  };
  const size_t h16bytes = sizeof(_Float16) * (size_t)ROWS * DD;  // 20.48 MB
  _Float16* hA     = (_Float16*)carve(h16bytes);
  _Float16* hB     = (_Float16*)carve(h16bytes);
  _Float16* aggH   = (_Float16*)carve(h16bytes);
  int*      cnt    = (int*)carve(sizeof(int) * NN);
  int*      cur    = (int*)carve(sizeof(int) * NN);
  int*      rowptr = (int*)carve(sizeof(int) * (NN + 1));
  int*      nbr    = (int*)carve(sizeof(int) * EE);
  float*    psum   = (float*)carve(sizeof(float) * (size_t)BB * CH * DD);
  float*    pmax   = (float*)carve(sizeof(float) * (size_t)BB * CH * DD);

  const int NODE_BLOCKS = 2048;
  const int NODE_WAVES = NODE_BLOCKS * 4;

  // encoder (fp16 out) + cnt zero (stream-ordered before k_deg)
  k_encoder<<<(NN * 512 / 8 + 255) / 256, 256, 0, stream>>>(x, Win, bin, hA, cnt);

  // CSR build: no memsets (cursor pre-initialized by k_scan)
  k_deg<<<(EE + 255) / 256, 256, 0, stream>>>(dst, cnt);
  k_scan<<<1, 1024, 0, stream>>>(cnt, rowptr, cur);
  k_fill<<<(EE + 255) / 256, 256, 0, stream>>>(src, dst, cur, nbr);

  // ---- layer 1 ----
  k_agg<<<(NN + 3) / 4, 256, 0, stream>>>(hA, rowptr, nbr, aggH);
  k_node_mfma<<<NODE_BLOCKS, 256, 0, stream>>>(hA, aggH, Ws1, Wm1, bias1, g1,
                                               be1, hB, NODE_WAVES);

  // ---- layer 2 ----
  k_agg<<<(NN + 3) / 4, 256, 0, stream>>>(hB, rowptr, nbr, aggH);
  k_node_mfma<<<NODE_BLOCKS, 256, 0, stream>>>(hB, aggH, Ws2, Wm2, bias2, g2,
                                               be2, hA, NODE_WAVES);

  // ---- readout + head ----
  k_reduce<<<BB * CH, 256, 0, stream>>>(hA, psum, pmax);
  k_final<<<1, 512, 0, stream>>>(psum, pmax, Wh1, bh1, Wh2, bh2, out);
}